// Round 4
// baseline (279.506 us; speedup 1.0000x reference)
//
#include <hip/hip_runtime.h>
#include <hip/hip_bf16.h>
#include <math.h>

#define DIM 768
#define CA  192

typedef __attribute__((ext_vector_type(8))) short short8;
typedef __attribute__((ext_vector_type(4))) float f32x4;

static __device__ __forceinline__ short f2bf(float f) {
    union { __hip_bfloat16 b; short s; } u;
    u.b = __float2bfloat16(f);
    return u.s;
}
static __device__ __forceinline__ float gelu_exact(float x) {
    return 0.5f * x * (1.0f + erff(x * 0.70710678118654752440f));
}

// ---------------------------------------------------------------------------
// Prep: w1 (768,192) -> w1T (192,768) bf16; w2 (192,768) -> w2T (768,192) bf16
// ---------------------------------------------------------------------------
__global__ void prep_kernel(const float* __restrict__ w1, const float* __restrict__ w2,
                            short* __restrict__ w1T, short* __restrict__ w2T) {
    int idx = blockIdx.x * 256 + threadIdx.x;
    if (idx < CA * DIM) {
        int n = idx / DIM, k = idx - n * DIM;
        w1T[idx] = f2bf(w1[k * CA + n]);
        int n2 = idx / CA, k2 = idx - n2 * CA;
        w2T[idx] = f2bf(w2[k2 * DIM + n2]);
    }
}

// ---------------------------------------------------------------------------
// GEMM1 fused, zero-LDS zero-barrier, occupancy-first.
// Wave tile: 16 rows x 48 cols (3 MFMA tiles). Block: 4 waves sharing the
// SAME 16 rows (A-frags L1-broadcast within the CU), covering all 192 cols.
// Grid 1568 = 196 l x 8 row-blocks -> ~6 waves/SIMD of TLP. B (w1T, 295 KB)
// is L2-resident. Reg double-buffer on A and B; no __syncthreads.
// Epilogue: temporal res via shfl_xor 16, gelu, bf16 store.
// ---------------------------------------------------------------------------
__global__ __launch_bounds__(256, 5) void gemm1_fused(
        const float* __restrict__ x, const short* __restrict__ w1T,
        const float* __restrict__ b1, const float* __restrict__ conv_w,
        const float* __restrict__ conv_b, short* __restrict__ gq) {
    const int bx   = blockIdx.x;            // 0..1567
    const int l    = (bx >> 3) + 1;         // 1..196
    const int rb   = bx & 7;
    const int wave = threadIdx.x >> 6, lane = threadIdx.x & 63;
    const int R0   = l * 128 + rb * 16;
    const int c0   = wave * 48;
    const int lm   = lane & 15, lg = lane >> 4;

    const float* xA = x   + (size_t)(R0 + lm) * DIM + lg * 8;
    const short* wB = w1T + (size_t)(c0 + lm) * DIM + lg * 8;

    f32x4 acc[3] = {};
    f32x4 a0 = *(const f32x4*)xA;
    f32x4 a1 = *(const f32x4*)(xA + 4);
    short8 bcur[3];
    #pragma unroll
    for (int j = 0; j < 3; j++) bcur[j] = *(const short8*)(wB + (size_t)j * 16 * DIM);

    for (int k = 0; k < 24; k++) {
        f32x4 a0n, a1n;
        short8 bnxt[3];
        if (k < 23) {
            const float* xn = xA + (k + 1) * 32;
            a0n = *(const f32x4*)xn;
            a1n = *(const f32x4*)(xn + 4);
            const short* wn = wB + (k + 1) * 32;
            #pragma unroll
            for (int j = 0; j < 3; j++) bnxt[j] = *(const short8*)(wn + (size_t)j * 16 * DIM);
        }
        short8 af;
        #pragma unroll
        for (int e = 0; e < 4; e++) { af[e] = f2bf(a0[e]); af[4 + e] = f2bf(a1[e]); }
        #pragma unroll
        for (int j = 0; j < 3; j++)
            acc[j] = __builtin_amdgcn_mfma_f32_16x16x32_bf16(af, bcur[j], acc[j], 0, 0, 0);
        a0 = a0n; a1 = a1n;
        #pragma unroll
        for (int j = 0; j < 3; j++) bcur[j] = bnxt[j];
    }

    // Epilogue: bias + temporal res (shfl_xor 16 over t-halves) + gelu -> bf16 g
    const int g1  = lg & 1;
    const int row = R0 + lg * 4;
    #pragma unroll
    for (int j = 0; j < 3; j++) {
        const int c = c0 + j * 16 + lm;
        const float b1c = b1[c];
        const float cw0 = conv_w[c * 3 + 0];
        const float cw1 = conv_w[c * 3 + 1];
        const float cw2 = conv_w[c * 3 + 2];
        const float cb  = conv_b[c];
        float hv[4];
        #pragma unroll
        for (int r = 0; r < 4; r++) hv[r] = acc[j][r] + b1c;
        float partial = 0.f;
        #pragma unroll
        for (int r = 0; r < 4; r++) {
            const int t = g1 * 4 + r;
            const float tf = (float)t;
            float coef = tf * cw1 - (7.0f - tf);
            if (t <= 6) coef += (tf + 1.0f) * cw0;
            if (t >= 1) coef += (tf - 1.0f) * cw2;
            partial += coef * hv[r];
        }
        const float res = cb + (partial + __shfl_xor(partial, 16)) * (1.0f / 28.0f);
        #pragma unroll
        for (int r = 0; r < 4; r++)
            gq[(size_t)(row + r) * CA + c] = f2bf(gelu_exact(hv[r] + res));
        if (l == 1) {   // out token 0 = gelu(h[l=1]), no res
            #pragma unroll
            for (int r = 0; r < 4; r++)
                gq[(size_t)(row - 128 + r) * CA + c] = f2bf(gelu_exact(hv[r]));
        }
    }
}

// ---------------------------------------------------------------------------
// GEMM2: out = x + g @ w2 + b2. M=25216, K=192, N=768.
// Zero-barrier K-loop (6 steps, reg dbuf, frags direct from L2/L3).
// Epilogue staged through LDS (64x132 fp32, 2-way-free bank pattern) so
// x-read / out-write are float4 with 512 B contiguity per 32 lanes.
// ---------------------------------------------------------------------------
__global__ __launch_bounds__(256, 4) void gemm2_kernel(
        const short* __restrict__ gq, const short* __restrict__ w2T,
        const float* __restrict__ b2, const float* __restrict__ x,
        float* __restrict__ out) {
    __shared__ __align__(16) float ots[64 * 132];

    const int tid = threadIdx.x;
    const int m0 = blockIdx.x * 64, n0 = blockIdx.y * 128;
    const int wave = tid >> 6, lane = tid & 63;
    const int wm = wave & 1, wn = wave >> 1;
    const int lm = lane & 15, lg = lane >> 4;
    const int mw = m0 + wm * 32, nw = n0 + wn * 64;

    const short* gA  = gq  + (size_t)(mw + lm) * CA + lg * 8;
    const short* wBp = w2T + (size_t)(nw + lm) * CA + lg * 8;

    f32x4 acc[2][4] = {};
    short8 ac[2], bc[4];
    #pragma unroll
    for (int i = 0; i < 2; i++) ac[i] = *(const short8*)(gA + i * 16 * CA);
    #pragma unroll
    for (int j = 0; j < 4; j++) bc[j] = *(const short8*)(wBp + j * 16 * CA);

    #pragma unroll
    for (int k = 0; k < 6; k++) {
        short8 an[2], bn[4];
        if (k < 5) {
            #pragma unroll
            for (int i = 0; i < 2; i++) an[i] = *(const short8*)(gA + i * 16 * CA + (k + 1) * 32);
            #pragma unroll
            for (int j = 0; j < 4; j++) bn[j] = *(const short8*)(wBp + j * 16 * CA + (k + 1) * 32);
        }
        #pragma unroll
        for (int i = 0; i < 2; i++)
            #pragma unroll
            for (int j = 0; j < 4; j++)
                acc[i][j] = __builtin_amdgcn_mfma_f32_16x16x32_bf16(ac[i], bc[j], acc[i][j], 0, 0, 0);
        #pragma unroll
        for (int i = 0; i < 2; i++) ac[i] = an[i];
        #pragma unroll
        for (int j = 0; j < 4; j++) bc[j] = bn[j];
    }

    // acc -> LDS (local row = wm*32 + i*16 + lg*4 + r, local col = wn*64 + j*16 + lm)
    #pragma unroll
    for (int i = 0; i < 2; i++) {
        const int rl = wm * 32 + i * 16 + lg * 4;
        #pragma unroll
        for (int j = 0; j < 4; j++) {
            const int cl = wn * 64 + j * 16 + lm;
            #pragma unroll
            for (int r = 0; r < 4; r++)
                ots[(rl + r) * 132 + cl] = acc[i][j][r];
        }
    }
    __syncthreads();

    // Cooperative coalesced write: 64 rows x 32 float4-chunks; 32 consecutive
    // lanes cover one 512 B row segment of x/out.
    #pragma unroll
    for (int s0 = 0; s0 < 8; s0++) {
        const int s = s0 * 256 + tid;
        const int row = s >> 5, c4 = (s & 31) * 4;
        f32x4 v = *(const f32x4*)&ots[row * 132 + c4];
        const size_t gidx = (size_t)(m0 + row) * DIM + n0 + c4;
        f32x4 xv = *(const f32x4*)(x + gidx);
        const float* bp = b2 + n0 + c4;
        #pragma unroll
        for (int e = 0; e < 4; e++) v[e] += xv[e] + bp[e];
        *(f32x4*)(out + gidx) = v;
    }
}

// ---------------------------------------------------------------------------
extern "C" void kernel_launch(void* const* d_in, const int* in_sizes, int n_in,
                              void* d_out, int out_size, void* d_ws, size_t ws_size,
                              hipStream_t stream) {
    (void)in_sizes; (void)n_in; (void)out_size; (void)ws_size;
    const float* x      = (const float*)d_in[0];
    const float* w1     = (const float*)d_in[1];
    const float* b1     = (const float*)d_in[2];
    const float* conv_w = (const float*)d_in[3];
    const float* conv_b = (const float*)d_in[4];
    const float* w2     = (const float*)d_in[5];
    const float* b2     = (const float*)d_in[6];
    float* out = (float*)d_out;

    char* ws = (char*)d_ws;
    short* g   = (short*)ws;                           // 25216*192*2 = 9,682,944 B
    short* w1T = (short*)(ws + 9682944);               // 294,912 B
    short* w2T = (short*)(ws + 9682944 + 294912);      // 294,912 B

    prep_kernel<<<(CA * DIM + 255) / 256, 256, 0, stream>>>(w1, w2, w1T, w2T);
    gemm1_fused<<<1568, 256, 0, stream>>>(x, w1T, b1, conv_w, conv_b, g);
    gemm2_kernel<<<dim3(394, 6), 256, 0, stream>>>(g, w2T, b2, x, out);
}

// Round 5
// 259.191 us; speedup vs baseline: 1.0784x; 1.0784x over previous
//
#include <hip/hip_runtime.h>
#include <hip/hip_bf16.h>
#include <math.h>

#define DIM 768
#define CA  192

typedef __attribute__((ext_vector_type(8))) short short8;
typedef __attribute__((ext_vector_type(4))) float f32x4;

static __device__ __forceinline__ short f2bf(float f) {
    union { __hip_bfloat16 b; short s; } u;
    u.b = __float2bfloat16(f);
    return u.s;
}
static __device__ __forceinline__ float bf2f(short s) {
    union { unsigned int u; float f; } v;
    v.u = ((unsigned int)(unsigned short)s) << 16;
    return v.f;
}
static __device__ __forceinline__ float gelu_exact(float x) {
    return 0.5f * x * (1.0f + erff(x * 0.70710678118654752440f));
}

// ---------------------------------------------------------------------------
// Prep: w1 (768,192) -> w1T (192,768) bf16; w2 (192,768) -> w2T (768,192) bf16
// ---------------------------------------------------------------------------
__global__ void prep_kernel(const float* __restrict__ w1, const float* __restrict__ w2,
                            short* __restrict__ w1T, short* __restrict__ w2T) {
    int idx = blockIdx.x * 256 + threadIdx.x;
    if (idx < CA * DIM) {
        int n = idx / DIM, k = idx - n * DIM;
        w1T[idx] = f2bf(w1[k * CA + n]);
        int n2 = idx / CA, k2 = idx - n2 * CA;
        w2T[idx] = f2bf(w2[k2 * DIM + n2]);
    }
}

// ---------------------------------------------------------------------------
// MEGA: gemm1 + temporal mix + gelu + gemm2 + residual, one kernel.
// Block = 32 rows of one l (4 complete t-groups), grid 784 = 196 l x 4.
// Phase1: h = x@w1+b1 per-wave (cols wave*48), zero-barrier direct-gather
//         K-loop (24 steps), A cvt fp32->bf16 in regs. x read ONCE from HBM.
// Phase2: temporal res via shfl_xor(16), gelu -> g in LDS (pitch 200).
//         l==1 blocks also export g0 = gelu(h) (no res) for the l=0 tail.
// Phase3: out = g@w2 + x + b2, 4 n-passes of 192 cols; B2 direct from
//         L2-resident w2T, A-frags from LDS g; epilogue staged via LDS so
//         x-read/out-write are coalesced f32x4 (x re-read served by L3).
// LDS 37.9 KB -> 4 blocks/CU. VGPR target ~100 (cap 128 via bounds(256,4)).
// ---------------------------------------------------------------------------
__global__ __launch_bounds__(256, 4) void mega_kernel(
        const float* __restrict__ x, const short* __restrict__ w1T,
        const short* __restrict__ w2T, const float* __restrict__ b1,
        const float* __restrict__ conv_w, const float* __restrict__ conv_b,
        const float* __restrict__ b2, short* __restrict__ g0,
        float* __restrict__ out) {
    __shared__ __align__(16) short gs[32 * 200];    // g tile, pitch 200 (bank-even)
    __shared__ __align__(16) float outs[32 * 196];  // out staging, pitch 196

    const int tid  = threadIdx.x;
    const int bx   = blockIdx.x;
    const int l    = (bx >> 2) + 1;     // 1..196
    const int rb   = bx & 3;
    const int R0   = l * 128 + rb * 32;
    const int wave = tid >> 6, lane = tid & 63;
    const int lm   = lane & 15, lg = lane >> 4;
    const int cw   = wave * 48;         // this wave's 48-col slice of CA

    // ---------------- Phase 1: h = x @ w1 + b1 (acc in regs) ----------------
    const float* xA = x   + (size_t)(R0 + lm) * DIM + lg * 8;
    const short* wB = w1T + (size_t)(cw + lm) * DIM + lg * 8;

    f32x4 acc[2][3] = {};
    f32x4 a[2][2];
    a[0][0] = *(const f32x4*)(xA);
    a[0][1] = *(const f32x4*)(xA + 4);
    a[1][0] = *(const f32x4*)(xA + 16 * DIM);
    a[1][1] = *(const f32x4*)(xA + 16 * DIM + 4);
    short8 bcur[3];
    #pragma unroll
    for (int j = 0; j < 3; j++) bcur[j] = *(const short8*)(wB + (size_t)j * 16 * DIM);

    for (int s = 0; s < 24; s++) {
        f32x4 an[2][2];
        short8 bn[3];
        if (s < 23) {
            const int o = (s + 1) * 32;
            an[0][0] = *(const f32x4*)(xA + o);
            an[0][1] = *(const f32x4*)(xA + o + 4);
            an[1][0] = *(const f32x4*)(xA + 16 * DIM + o);
            an[1][1] = *(const f32x4*)(xA + 16 * DIM + o + 4);
            #pragma unroll
            for (int j = 0; j < 3; j++) bn[j] = *(const short8*)(wB + (size_t)j * 16 * DIM + o);
        }
        short8 af[2];
        #pragma unroll
        for (int i = 0; i < 2; i++)
            #pragma unroll
            for (int e = 0; e < 4; e++) {
                af[i][e]     = f2bf(a[i][0][e]);
                af[i][4 + e] = f2bf(a[i][1][e]);
            }
        #pragma unroll
        for (int i = 0; i < 2; i++)
            #pragma unroll
            for (int j = 0; j < 3; j++)
                acc[i][j] = __builtin_amdgcn_mfma_f32_16x16x32_bf16(af[i], bcur[j], acc[i][j], 0, 0, 0);
        #pragma unroll
        for (int i = 0; i < 2; i++) { a[i][0] = an[i][0]; a[i][1] = an[i][1]; }
        #pragma unroll
        for (int j = 0; j < 3; j++) bcur[j] = bn[j];
    }

    // ------------- Phase 2: temporal mix + gelu -> g in LDS -----------------
    const int g1 = lg & 1;
    #pragma unroll
    for (int j = 0; j < 3; j++) {
        const int c = cw + j * 16 + lm;
        const float b1c = b1[c];
        const float cw0 = conv_w[c * 3 + 0];
        const float cw1 = conv_w[c * 3 + 1];
        const float cw2 = conv_w[c * 3 + 2];
        const float cb  = conv_b[c];
        #pragma unroll
        for (int i = 0; i < 2; i++) {
            float hv[4];
            #pragma unroll
            for (int r = 0; r < 4; r++) hv[r] = acc[i][j][r] + b1c;
            float partial = 0.f;
            #pragma unroll
            for (int r = 0; r < 4; r++) {
                const int t = g1 * 4 + r;
                const float tf = (float)t;
                float coef = tf * cw1 - (7.0f - tf);
                if (t <= 6) coef += (tf + 1.0f) * cw0;
                if (t >= 1) coef += (tf - 1.0f) * cw2;
                partial += coef * hv[r];
            }
            const float res = cb + (partial + __shfl_xor(partial, 16)) * (1.0f / 28.0f);
            const int rowl = 16 * i + lg * 4;
            #pragma unroll
            for (int r = 0; r < 4; r++)
                gs[(rowl + r) * 200 + c] = f2bf(gelu_exact(hv[r] + res));
            if (l == 1) {   // export g0 = gelu(h[l=1]) for the l=0 tail kernel
                #pragma unroll
                for (int r = 0; r < 4; r++)
                    g0[(size_t)(rb * 32 + rowl + r) * CA + c] = f2bf(gelu_exact(hv[r]));
            }
        }
    }
    __syncthreads();

    // ------------- Phase 3: out = g @ w2 + x + b2, 4 n-passes ---------------
    for (int p = 0; p < 4; p++) {
        if (p) __syncthreads();          // outs consumed by previous pass
        const int n0 = p * 192;
        const short* wB2 = w2T + (size_t)(n0 + cw + lm) * CA + lg * 8;

        f32x4 acc3[2][3] = {};
        #pragma unroll
        for (int s = 0; s < 6; s++) {
            short8 af[2], bf[3];
            #pragma unroll
            for (int i = 0; i < 2; i++)
                af[i] = *(const short8*)&gs[(16 * i + lm) * 200 + s * 32 + lg * 8];
            #pragma unroll
            for (int j = 0; j < 3; j++)
                bf[j] = *(const short8*)(wB2 + (size_t)j * 16 * CA + s * 32);
            #pragma unroll
            for (int i = 0; i < 2; i++)
                #pragma unroll
                for (int j = 0; j < 3; j++)
                    acc3[i][j] = __builtin_amdgcn_mfma_f32_16x16x32_bf16(af[i], bf[j], acc3[i][j], 0, 0, 0);
        }

        // stage to LDS (2-way-free bank pattern), then coalesced write-out
        #pragma unroll
        for (int i = 0; i < 2; i++) {
            const int rowl = 16 * i + lg * 4;
            #pragma unroll
            for (int j = 0; j < 3; j++) {
                const int cl = cw + j * 16 + lm;
                #pragma unroll
                for (int r = 0; r < 4; r++)
                    outs[(rowl + r) * 196 + cl] = acc3[i][j][r];
            }
        }
        __syncthreads();
        #pragma unroll
        for (int q = 0; q < 6; q++) {
            const int s = q * 256 + tid;
            const int row = s / 48, c4 = (s % 48) * 4;
            f32x4 v = *(const f32x4*)&outs[row * 196 + c4];
            const int gcol = n0 + c4;
            const size_t gidx = (size_t)(R0 + row) * DIM + gcol;
            const f32x4 xv = *(const f32x4*)(x + gidx);
            const f32x4 bv = *(const f32x4*)(b2 + gcol);
            #pragma unroll
            for (int e = 0; e < 4; e++) v[e] += xv[e] + bv[e];
            *(f32x4*)(out + gidx) = v;
        }
    }
}

// ---------------------------------------------------------------------------
// Tail: out rows l=0 (128 rows): out[bt,c] = x[bt,c] + b2[c] + g0[bt,:]@w2T[c,:]
// One thread per output element; g0/w2T rows are L1/L2-hot.
// ---------------------------------------------------------------------------
__global__ __launch_bounds__(256) void tail_kernel(
        const short* __restrict__ g0, const short* __restrict__ w2T,
        const float* __restrict__ b2, const float* __restrict__ x,
        float* __restrict__ out) {
    const int e = blockIdx.x * 256 + threadIdx.x;   // 0..98303
    const int bt = e / DIM, c = e - bt * DIM;
    const short* gr = g0  + (size_t)bt * CA;
    const short* wr = w2T + (size_t)c * CA;
    float sum = 0.f;
    #pragma unroll
    for (int kc = 0; kc < 24; kc++) {
        short8 gv = *(const short8*)(gr + kc * 8);
        short8 wv = *(const short8*)(wr + kc * 8);
        #pragma unroll
        for (int e2 = 0; e2 < 8; e2++) sum += bf2f(gv[e2]) * bf2f(wv[e2]);
    }
    out[e] = x[e] + b2[c] + sum;
}

// ---------------------------------------------------------------------------
extern "C" void kernel_launch(void* const* d_in, const int* in_sizes, int n_in,
                              void* d_out, int out_size, void* d_ws, size_t ws_size,
                              hipStream_t stream) {
    (void)in_sizes; (void)n_in; (void)out_size; (void)ws_size;
    const float* x      = (const float*)d_in[0];
    const float* w1     = (const float*)d_in[1];
    const float* b1     = (const float*)d_in[2];
    const float* conv_w = (const float*)d_in[3];
    const float* conv_b = (const float*)d_in[4];
    const float* w2     = (const float*)d_in[5];
    const float* b2     = (const float*)d_in[6];
    float* out = (float*)d_out;

    char* ws = (char*)d_ws;
    short* w1T = (short*)ws;                          // 294,912 B
    short* w2T = (short*)(ws + 294912);               // 294,912 B
    short* g0  = (short*)(ws + 294912 + 294912);      //  49,152 B

    prep_kernel<<<(CA * DIM + 255) / 256, 256, 0, stream>>>(w1, w2, w1T, w2T);
    mega_kernel<<<784, 256, 0, stream>>>(x, w1T, w2T, b1, conv_w, conv_b, b2, g0, out);
    tail_kernel<<<384, 256, 0, stream>>>(g0, w2T, b2, x, out);
}